// Round 1
// baseline (2483.015 us; speedup 1.0000x reference)
//
#include <hip/hip_runtime.h>

#define B_TOTAL 262144
#define T_STEPS 15
#define H 64
#define BLOCK 128

__device__ __forceinline__ float fsigmoid(float x) {
    // sigmoid(x) = 1/(1+exp(-x)); v_exp_f32 + v_rcp_f32, ~1 ulp each
    float e = __expf(-x);
    return __builtin_amdgcn_rcpf(1.0f + e);
}

__device__ __forceinline__ float ftanh(float x) {
    // tanh(x) = 2*sigmoid(2x) - 1; saturates cleanly (exp->inf -> rcp->0 -> -1)
    float e = __expf(-2.0f * x);
    return 2.0f * __builtin_amdgcn_rcpf(1.0f + e) - 1.0f;
}

__global__ __launch_bounds__(BLOCK) void gru_fp32_kernel(
    const float* __restrict__ x,     // (B, 15)
    const float* __restrict__ W_ih,  // (192, 1)
    const float* __restrict__ W_hh,  // (192, 64)
    const float* __restrict__ b_ih,  // (192,)
    const float* __restrict__ b_hh,  // (192,)
    const float* __restrict__ W_fc,  // (2, 64)
    const float* __restrict__ b_fc,  // (2,)
    float* __restrict__ out)         // (B, 2)
{
    // Per-thread new-h double buffer; lane-consecutive inner dim -> conflict-free.
    __shared__ float hbuf[H][BLOCK];   // 32 KiB @ BLOCK=128

    const int tid = threadIdx.x;
    const int seq = blockIdx.x * BLOCK + tid;   // grid exactly covers B

    float h[H];
#pragma unroll
    for (int k = 0; k < H; ++k) {
        h[k] = 0.0f;
        hbuf[k][tid] = 0.0f;
    }

    for (int t = 0; t < T_STEPS; ++t) {
        const float xt = x[seq * T_STEPS + t];

        // j is a uniform loop counter -> W_hh/W_ih/b_* loads are wave-uniform
        // (expect s_load scalarization; FMA operands come from SGPRs).
        for (int j = 0; j < H; ++j) {
            float ar = 0.0f, az = 0.0f, an = 0.0f;
#pragma unroll
            for (int k = 0; k < H; ++k) {
                ar += h[k] * W_hh[j * H + k];
                az += h[k] * W_hh[(H + j) * H + k];
                an += h[k] * W_hh[(2 * H + j) * H + k];
            }
            const float gr = fsigmoid(xt * W_ih[j]         + b_ih[j]         + ar + b_hh[j]);
            const float gz = fsigmoid(xt * W_ih[H + j]     + b_ih[H + j]     + az + b_hh[H + j]);
            const float gn = ftanh(   xt * W_ih[2 * H + j] + b_ih[2 * H + j] + gr * (an + b_hh[2 * H + j]));

            const float h_old = hbuf[j][tid];          // prev-timestep h[j] (runtime j -> LDS, not regs)
            hbuf[j][tid] = (1.0f - gz) * gn + gz * h_old;
        }

        // Commit new h into registers (all same-thread LDS; no barrier needed).
#pragma unroll
        for (int k = 0; k < H; ++k) h[k] = hbuf[k][tid];
    }

    // FC head: logits[c] = sum_k h[k]*W_fc[c*H+k] + b_fc[c]
    float acc0 = b_fc[0];
    float acc1 = b_fc[1];
#pragma unroll
    for (int k = 0; k < H; ++k) {
        acc0 += h[k] * W_fc[k];
        acc1 += h[k] * W_fc[H + k];
    }
    out[seq * 2 + 0] = acc0;
    out[seq * 2 + 1] = acc1;
}

extern "C" void kernel_launch(void* const* d_in, const int* in_sizes, int n_in,
                              void* d_out, int out_size, void* d_ws, size_t ws_size,
                              hipStream_t stream) {
    const float* x    = (const float*)d_in[0];
    const float* W_ih = (const float*)d_in[1];
    const float* W_hh = (const float*)d_in[2];
    const float* b_ih = (const float*)d_in[3];
    const float* b_hh = (const float*)d_in[4];
    const float* W_fc = (const float*)d_in[5];
    const float* b_fc = (const float*)d_in[6];
    float* out = (float*)d_out;

    dim3 grid(B_TOTAL / BLOCK);
    dim3 block(BLOCK);
    gru_fp32_kernel<<<grid, block, 0, stream>>>(x, W_ih, W_hh, b_ih, b_hh, W_fc, b_fc, out);
}

// Round 2
// 251.264 us; speedup vs baseline: 9.8821x; 9.8821x over previous
//
#include <hip/hip_runtime.h>

#define T_STEPS 15
#define HDIM 64
#define ROWS_PER_BLOCK 64
#define B_TOTAL 262144

typedef _Float16 half8 __attribute__((ext_vector_type(8)));
typedef _Float16 half4 __attribute__((ext_vector_type(4)));
typedef float f32x4 __attribute__((ext_vector_type(4)));

__device__ __forceinline__ float fsigmoid(float v) {
    float e = __expf(-v);
    return __builtin_amdgcn_rcpf(1.0f + e);
}
__device__ __forceinline__ float ftanh(float v) {
    float e = __expf(-2.0f * v);
    return 2.0f * __builtin_amdgcn_rcpf(1.0f + e) - 1.0f;
}

// Swizzled element index into a [rows][64] fp16 LDS tile.
// XOR of (row&7)<<3 elements (= <<4 bytes) breaks the 128B row stride
// bank conflict (T2 / Guideline-4 pattern); preserves 8B/16B alignment.
__device__ __forceinline__ int swz(int row, int e) {
    return (row * 64 + e) ^ ((row & 7) << 3);
}

__global__ __launch_bounds__(256, 2) void gru_mfma_kernel(
    const float* __restrict__ x,     // (B,15)
    const float* __restrict__ W_ih,  // (192,1)
    const float* __restrict__ W_hh,  // (192,64)
    const float* __restrict__ b_ih,  // (192,)
    const float* __restrict__ b_hh,  // (192,)
    const float* __restrict__ W_fc,  // (2,64)
    const float* __restrict__ b_fc,  // (2,)
    float* __restrict__ out)         // (B,2)
{
    __shared__ _Float16 wlds[192 * 64];                 // 24576 B, B-matrix (swizzled, k-permuted)
    __shared__ float    xlds[ROWS_PER_BLOCK * T_STEPS]; // 3840 B
    __shared__ _Float16 hst[4][2][16 * 64];             // per-wave h hi/lo, 16384 B

    const int tid  = threadIdx.x;
    const int wave = tid >> 6;
    const int lane = tid & 63;
    const int c    = lane & 15;   // N-col / A-row / reduce-group index
    const int g4   = lane >> 4;   // k-slot group / C-row group
    const int r0   = blockIdx.x * ROWS_PER_BLOCK;

    // ---- stage B = W_hh^T with k-dim permuted by invs(s)=(s&3)*16+(s>>2) ----
    // stored s corresponds to hidden index jn=invs(s); the h-store uses the
    // same s-space, so the MFMA k-permutation cancels.
    for (int idx = tid; idx < 192 * 64; idx += 256) {
        int n = idx >> 6, s = idx & 63;
        int korig = (s & 3) * 16 + (s >> 2);
        wlds[swz(n, s)] = (_Float16)W_hh[n * 64 + korig];
    }
    for (int idx = tid; idx < ROWS_PER_BLOCK * T_STEPS; idx += 256)
        xlds[idx] = x[r0 * T_STEPS + idx];
    __syncthreads();

    // ---- B fragments, register-resident: 12 N-tiles x 2 k-steps ----
    half8 Bf[12][2];
#pragma unroll
    for (int tn = 0; tn < 12; ++tn)
#pragma unroll
        for (int s2 = 0; s2 < 2; ++s2)
            Bf[tn][s2] = *(const half8*)&wlds[swz(tn * 16 + c, s2 * 32 + g4 * 8)];

    // ---- per-lane gate constants (jn = tq*16 + c) ----
    float wihr[4], wihz[4], wihn[4], seedr[4], seedz[4], seedn[4], bihn[4];
#pragma unroll
    for (int tq = 0; tq < 4; ++tq) {
        int jn = tq * 16 + c;
        wihr[tq]  = W_ih[jn];
        wihz[tq]  = W_ih[64 + jn];
        wihn[tq]  = W_ih[128 + jn];
        seedr[tq] = b_ih[jn] + b_hh[jn];
        seedz[tq] = b_ih[64 + jn] + b_hh[64 + jn];
        seedn[tq] = b_hh[128 + jn];     // must stay inside r*(.) per reference
        bihn[tq]  = b_ih[128 + jn];
    }

    f32x4 accr[4], accz[4], accn[4];
#pragma unroll
    for (int tq = 0; tq < 4; ++tq) {
        accr[tq] = (f32x4){seedr[tq], seedr[tq], seedr[tq], seedr[tq]};
        accz[tq] = (f32x4){seedz[tq], seedz[tq], seedz[tq], seedz[tq]};
        accn[tq] = (f32x4){seedn[tq], seedn[tq], seedn[tq], seedn[tq]};
    }

    float h[4][4];  // [tq][reg] fp32 h at C-layout slot (row=g4*4+reg, jn=tq*16+c)
#pragma unroll
    for (int tq = 0; tq < 4; ++tq)
#pragma unroll
        for (int reg = 0; reg < 4; ++reg) h[tq][reg] = 0.0f;

    _Float16* hhi = hst[wave][0];
    _Float16* hlo = hst[wave][1];

    for (int t = 0; t < T_STEPS; ++t) {
        if (t > 0) {
            // A fragments: row = lane&15 = c, k-slots s2*32 + g4*8 + i (same
            // slot->k bijection as the B fill -> permutation cancels).
            half8 Ahi[2], Alo[2];
#pragma unroll
            for (int s2 = 0; s2 < 2; ++s2) {
                Ahi[s2] = *(const half8*)&hhi[swz(c, s2 * 32 + g4 * 8)];
                Alo[s2] = *(const half8*)&hlo[swz(c, s2 * 32 + g4 * 8)];
            }
#pragma unroll
            for (int tq = 0; tq < 4; ++tq) {
#pragma unroll
                for (int s2 = 0; s2 < 2; ++s2) {
                    accr[tq] = __builtin_amdgcn_mfma_f32_16x16x32_f16(Ahi[s2], Bf[tq][s2],     accr[tq], 0, 0, 0);
                    accz[tq] = __builtin_amdgcn_mfma_f32_16x16x32_f16(Ahi[s2], Bf[4 + tq][s2], accz[tq], 0, 0, 0);
                    accn[tq] = __builtin_amdgcn_mfma_f32_16x16x32_f16(Ahi[s2], Bf[8 + tq][s2], accn[tq], 0, 0, 0);
                    accn[tq] = __builtin_amdgcn_mfma_f32_16x16x32_f16(Alo[s2], Bf[8 + tq][s2], accn[tq], 0, 0, 0);
                }
            }
        }

        // ---- gates (fp32 VALU), h_old is register-local in C-layout ----
        float xt[4];
#pragma unroll
        for (int reg = 0; reg < 4; ++reg)
            xt[reg] = xlds[(wave * 16 + g4 * 4 + reg) * T_STEPS + t];

#pragma unroll
        for (int reg = 0; reg < 4; ++reg) {
            half4 vh, vl;
#pragma unroll
            for (int tq = 0; tq < 4; ++tq) {
                float pr = accr[tq][reg] + xt[reg] * wihr[tq];
                float pz = accz[tq][reg] + xt[reg] * wihz[tq];
                float rg = fsigmoid(pr);
                float zg = fsigmoid(pz);
                float na = __builtin_fmaf(rg, accn[tq][reg],
                            __builtin_fmaf(xt[reg], wihn[tq], bihn[tq]));
                float ng = ftanh(na);
                float hn = __builtin_fmaf(zg, h[tq][reg] - ng, ng);
                h[tq][reg] = hn;
                _Float16 hi16 = (_Float16)hn;
                vh[tq] = hi16;
                vl[tq] = (_Float16)(hn - (float)hi16);
            }
            // store h at s = c*4 + tq  (consecutive -> one b64 write each)
            int row = g4 * 4 + reg;
            *(half4*)&hhi[swz(row, c * 4)] = vh;
            *(half4*)&hlo[swz(row, c * 4)] = vl;
        }
        // reseed accumulators for next timestep
#pragma unroll
        for (int tq = 0; tq < 4; ++tq) {
            accr[tq] = (f32x4){seedr[tq], seedr[tq], seedr[tq], seedr[tq]};
            accz[tq] = (f32x4){seedz[tq], seedz[tq], seedz[tq], seedz[tq]};
            accn[tq] = (f32x4){seedn[tq], seedn[tq], seedn[tq], seedn[tq]};
        }
    }

    // ---- FC head: logits from exact fp32 h, shuffle-reduce over c ----
    float wfc0[4], wfc1[4];
#pragma unroll
    for (int tq = 0; tq < 4; ++tq) {
        wfc0[tq] = W_fc[tq * 16 + c];
        wfc1[tq] = W_fc[64 + tq * 16 + c];
    }
#pragma unroll
    for (int reg = 0; reg < 4; ++reg) {
        float s0 = 0.0f, s1 = 0.0f;
#pragma unroll
        for (int tq = 0; tq < 4; ++tq) {
            s0 = __builtin_fmaf(h[tq][reg], wfc0[tq], s0);
            s1 = __builtin_fmaf(h[tq][reg], wfc1[tq], s1);
        }
#pragma unroll
        for (int m = 1; m < 16; m <<= 1) {
            s0 += __shfl_xor(s0, m, 64);
            s1 += __shfl_xor(s1, m, 64);
        }
        if (c == 0) {
            int gr = r0 + wave * 16 + g4 * 4 + reg;
            out[gr * 2 + 0] = s0 + b_fc[0];
            out[gr * 2 + 1] = s1 + b_fc[1];
        }
    }
}

extern "C" void kernel_launch(void* const* d_in, const int* in_sizes, int n_in,
                              void* d_out, int out_size, void* d_ws, size_t ws_size,
                              hipStream_t stream) {
    const float* x    = (const float*)d_in[0];
    const float* W_ih = (const float*)d_in[1];
    const float* W_hh = (const float*)d_in[2];
    const float* b_ih = (const float*)d_in[3];
    const float* b_hh = (const float*)d_in[4];
    const float* W_fc = (const float*)d_in[5];
    const float* b_fc = (const float*)d_in[6];
    float* out = (float*)d_out;

    dim3 grid(B_TOTAL / ROWS_PER_BLOCK);
    dim3 block(256);
    gru_mfma_kernel<<<grid, block, 0, stream>>>(x, W_ih, W_hh, b_ih, b_hh, W_fc, b_fc, out);
}